// Round 5
// baseline (233.837 us; speedup 1.0000x reference)
//
#include <hip/hip_runtime.h>

#define NB 16
#define NC 8
#define HW (512 * 512)
#define BLOCKS_PER_B 32
#define NTHREADS 256
#define NBLOCKS (BLOCKS_PER_B * NB)   // 512 = exactly 2 blocks/CU on 256 CUs
#define STRIDE (BLOCKS_PER_B * NTHREADS)  // 8192 float4-groups; 65536/8192 = 8 iters exact

// ws layout (floats): [0, NB*64)            : S[b][ci][ck]
//                     [NB*64, NB*64+NB*8)   : n[b][ck]
//                     [NB*72]               : ce_sum
//                     [NB*72+1]             : block-done counter (as uint32)
#define WS_FLOATS (NB * NC * NC + NB * NC + 2)
#define CTR_IDX (NB * NC * NC + NB * NC + 1)

__device__ __forceinline__ float wave_reduce(float v) {
#pragma unroll
  for (int off = 32; off > 0; off >>= 1) v += __shfl_xor(v, off, 64);
  return v;
}

// Register-level double-buffered streaming pass.
// __launch_bounds__(256,2): VGPR cap 256. Need ~190 (S=64, 2x9 float4/int4
// in-flight loads=72, pv/cnt/addr/temps). Round-3 evidence: cap 128 spilled S
// (VGPR_Count=64, 34MB scratch writes, 86.8us @17% HBM). Registers > waves.
__global__ __launch_bounds__(NTHREADS, 2)
void jce_main(const float* __restrict__ pred, const int* __restrict__ target,
              float* __restrict__ ws, float* __restrict__ out) {
  const int b = blockIdx.y;
  const int tid = threadIdx.x;
  const float* predb = pred + (size_t)b * NC * HW;
  const int4* tgt4 = (const int4*)(target + (size_t)b * HW);
  const int g0 = blockIdx.x * NTHREADS + tid;  // 0..8191, all 8 strided iters in-bounds

  float S[NC][NC];
  float cnt[NC];
  float ce = 0.0f;
#pragma unroll
  for (int i = 0; i < NC; ++i) {
    cnt[i] = 0.0f;
#pragma unroll
    for (int k = 0; k < NC; ++k) S[i][k] = 0.0f;
  }

  // ---- software pipeline: two named load sets (static indexing only) ----
  int4 tA, tB;
  float4 pA[NC], pB[NC];

#define LOAD(T, P, s)                                                      \
  do {                                                                     \
    const int gg = g0 + (s) * STRIDE;                                      \
    T = tgt4[gg];                                                          \
    _Pragma("unroll") for (int c = 0; c < NC; ++c)                         \
        P[c] = ((const float4*)(predb + (size_t)c * HW))[gg];              \
  } while (0)

#define COMPUTE(T, P)                                                      \
  do {                                                                     \
    _Pragma("unroll") for (int j = 0; j < 4; ++j) {                        \
      const int tc = (j == 0) ? T.x : (j == 1) ? T.y : (j == 2) ? T.z : T.w; \
      float pv[NC];                                                        \
      _Pragma("unroll") for (int c = 0; c < NC; ++c)                       \
          pv[c] = (j == 0) ? P[c].x : (j == 1) ? P[c].y                    \
                  : (j == 2) ? P[c].z : P[c].w;                            \
      float es = 0.0f;                                                     \
      _Pragma("unroll") for (int c = 0; c < NC; ++c) es += __expf(pv[c]);  \
      const float lse = __logf(es);                                        \
      float ptc = 0.0f;                                                    \
      _Pragma("unroll") for (int k = 0; k < NC; ++k) {                     \
        const float msk = (tc == k) ? 1.0f : 0.0f;                         \
        cnt[k] += msk;                                                     \
        ptc = fmaf(msk, pv[k], ptc);                                       \
        _Pragma("unroll") for (int ci = 0; ci < NC; ++ci)                  \
            S[ci][k] = fmaf(msk, pv[ci], S[ci][k]);                        \
      }                                                                    \
      ce += lse - ptc;                                                     \
    }                                                                      \
  } while (0)

  LOAD(tA, pA, 0);
#pragma unroll
  for (int s = 0; s < 8; s += 2) {
    if (s + 1 < 8) LOAD(tB, pB, s + 1);  // B's 9 loads in flight during A's compute
    COMPUTE(tA, pA);
    if (s + 2 < 8) LOAD(tA, pA, s + 2);  // A's next loads in flight during B's compute
    if (s + 1 < 8) COMPUTE(tB, pB);
  }
#undef LOAD
#undef COMPUTE

  // ---- wave butterfly reduction of the 73 partials ----
#pragma unroll
  for (int i = 0; i < NC; ++i) {
#pragma unroll
    for (int k = 0; k < NC; ++k) S[i][k] = wave_reduce(S[i][k]);
    cnt[i] = wave_reduce(cnt[i]);
  }
  ce = wave_reduce(ce);

  // ---- cross-wave via LDS, one atomicAdd per value per block ----
  __shared__ float red[NTHREADS / 64][NC * NC + NC + 1];
  const int wave = tid >> 6, lane = tid & 63;
  if (lane == 0) {
#pragma unroll
    for (int i = 0; i < NC; ++i) {
#pragma unroll
      for (int k = 0; k < NC; ++k) red[wave][i * NC + k] = S[i][k];
      red[wave][NC * NC + i] = cnt[i];
    }
    red[wave][NC * NC + NC] = ce;
  }
  __syncthreads();
  if (tid < NC * NC + NC + 1) {
    float v = 0.0f;
#pragma unroll
    for (int w = 0; w < NTHREADS / 64; ++w) v += red[w][tid];
    if (tid < NC * NC)
      atomicAdd(&ws[b * (NC * NC) + tid], v);
    else if (tid < NC * NC + NC)
      atomicAdd(&ws[NB * NC * NC + b * NC + (tid - NC * NC)], v);
    else
      atomicAdd(&ws[NB * NC * NC + NB * NC], v);
  }

  // ---- last-block-done finalize (saves a kernel launch) ----
  __shared__ int is_last;
  __syncthreads();           // all atomics above issued & drained (waitcnt before barrier)
  if (tid == 0) {
    __threadfence();         // release our atomics before the counter bump
    unsigned prev = atomicAdd((unsigned*)&ws[CTR_IDX], 1u);
    is_last = (prev == (unsigned)(NBLOCKS - 1)) ? 1 : 0;
  }
  __syncthreads();
  if (!is_last) return;

  // This block saw all NBLOCKS counter bumps -> all S/cnt/ce atomics complete.
  // Read partials with atomicAdd(p, 0.0f): guaranteed device-coherent
  // (plain loads could hit a stale per-XCD L2).
  float acc = 0.0f;
  for (int idx = tid; idx < NB * NC * NC; idx += NTHREADS) {
    const int bb = idx >> 6, ci = (idx >> 3) & 7, ck = idx & 7;
    if (ci == ck) continue;
    const float n_ck = atomicAdd(&ws[NB * NC * NC + bb * NC + ck], 0.0f);
    const float n_ci = atomicAdd(&ws[NB * NC * NC + bb * NC + ci], 0.0f);
    const float Sik = atomicAdd(&ws[bb * (NC * NC) + ci * NC + ck], 0.0f);
    const float Sii = atomicAdd(&ws[bb * (NC * NC) + ci * NC + ci], 0.0f);
    acc += logf(0.5f + 0.5f * (Sii / n_ci - Sik / n_ck));
  }
  acc = wave_reduce(acc);
  __shared__ float red2[NTHREADS / 64];
  if (lane == 0) red2[wave] = acc;
  __syncthreads();
  if (tid == 0) {
    float tot = 0.0f;
#pragma unroll
    for (int w = 0; w < NTHREADS / 64; ++w) tot += red2[w];
    const float jl = -tot / (float)NB;
    const float cesum = atomicAdd(&ws[NB * NC * NC + NB * NC], 0.0f);
    out[0] = jl + cesum / ((float)NB * (float)HW);
  }
}

extern "C" void kernel_launch(void* const* d_in, const int* in_sizes, int n_in,
                              void* d_out, int out_size, void* d_ws, size_t ws_size,
                              hipStream_t stream) {
  const float* pred = (const float*)d_in[0];
  const int* target = (const int*)d_in[1];
  float* out = (float*)d_out;
  float* ws = (float*)d_ws;

  hipMemsetAsync(ws, 0, WS_FLOATS * sizeof(float), stream);
  dim3 grid(BLOCKS_PER_B, NB);
  jce_main<<<grid, NTHREADS, 0, stream>>>(pred, target, ws, out);
}